// Round 15
// baseline (836.965 us; speedup 1.0000x reference)
//
#include <hip/hip_runtime.h>
#include <type_traits>

// Problem constants (from reference):
//   B=100000, R1=1, N1=200, N2=200, N3=50, R2=32
//   TT_core: (1,200,200,50,32) f32  = 64,000,000 elems (256 MB)
//   K1,K2: (200,200) f32; K3: (50,50) f32; indices: (B,3) int (values in [0,50))
//   out = (T3 gathered)[B,1,32] (3.2M f32), reg = T3*TT (64M f32)
// d_out layout: [0,3.2M) out, [3.2M, 67.2M) reg.
//
// Round-15: persistent-A zero-barrier contraction. R10-R14 invariant: ci/cj
// pinned 160-175us across 5 LDS/barrier/occupancy structures, all pipes <25%
// -> the per-phase barrier+full-drain serialization is structural (m233).
// Now: A (93KB fp16) resides WHOLE in LDS (stride 232 halves: 29 chunks,
// 5 mod 8 -> uniform 8/bank b128 reads, 16B-aligned); ONE barrier; then a
// 10-iter loop over n-tiles of 128 with ZERO barriers: issue next tile's 56
// B-loads, cvt+MFMA current (counted vmcnt keeps next set in flight - T4),
// store. Grid 250 = 1 block/CU exactly, no tail. 512 thr, 2 waves/SIMD.

typedef float    f32x4 __attribute__((ext_vector_type(4)));
typedef float    f32x8 __attribute__((ext_vector_type(8)));
typedef _Float16 half8 __attribute__((ext_vector_type(8)));
typedef unsigned short ushort8 __attribute__((ext_vector_type(8)));
typedef unsigned short u16;
typedef unsigned int   u32;

#define N12   200
#define N3    50
#define R2    32
#define SJK   320000          // stride of i in TT == N2*N3*R2; also stride of a in T1
#define SKS   1600            // stride of j / b  == N3*R2
#define NTOT  64000000
#define OUT_ELEMS 3200000     // B*32
#define APAD  208             // padded rows of K matrices (13 * 16)
#define KPAD  224             // padded contraction dim (7 * 32)
#define LSTR  232             // persistent-A LDS row stride (29 chunks, 5 mod 8)
#define K3B_HALVES 4096       // 2 kstep * 4 csub * 64 lane * 8 e

// ---------------- prep: K1,K2 -> padded fp16 [208][224]; K3 -> B-frag pack --
__global__ __launch_bounds__(256) void k_prep(
    const float* __restrict__ K1, const float* __restrict__ K2,
    const float* __restrict__ K3, u16* __restrict__ kh) {
  int t = blockIdx.x * 256 + threadIdx.x;
  const int total = APAD * KPAD;
  if (t >= 2 * total + K3B_HALVES) return;
  float x;
  if (t < 2 * total) {
    const float* src = (t < total) ? K1 : K2;
    int tt = (t < total) ? t : t - total;
    int r = tt / KPAD, c = tt % KPAD;
    x = (r < N12 && c < N12) ? src[r * N12 + c] : 0.f;
  } else {
    int u = t - 2 * total;
    int e = u & 7, l = (u >> 3) & 63, frag = u >> 9;   // frag = kstep*4+csub
    int c = (frag & 3) * 16 + (l & 15);
    int k = (frag >> 2) * 32 + (l >> 4) * 8 + e;
    x = (c < N3 && k < N3) ? K3[c * N3 + k] : 0.f;
  }
  kh[t] = __builtin_bit_cast(u16, (_Float16)x);
}

// ----------- persistent-A contraction: D[row,n] = sum_k K[row,k]*B[k,n] ----
// NB = columns per batch (ci: 320000 single batch; cj: 1600 per a).
// 512 threads; each wave owns a 16-col subtile of the 128-col tile; 10 tiles
// per block, grid 250 (exact). B double-register-set (BA/BB) prefetch.
#define PLOAD(TILE, BS)                                                       \
  { const int c0 = (TILE)*128 + wave*16;                                      \
    const int ai = c0 / NB;                                                   \
    const BT* bp = Bsrc + (long)ai*bStrideB + (c0 - ai*NB) + l15;             \
    _Pragma("unroll")                                                         \
    for (int s = 0; s < 7; ++s) {                                             \
      _Pragma("unroll")                                                       \
      for (int e = 0; e < 8; ++e) {                                           \
        int kr = s*32 + kq + e; if (kr > 199) kr = 199;                       \
        BS[s][e] = bp[(long)kr * ldB]; } } }

#define PCVT(BS)                                                              \
  { _Pragma("unroll")                                                         \
    for (int s = 0; s < 7; ++s)                                               \
      _Pragma("unroll")                                                       \
      for (int e = 0; e < 8; ++e) {                                           \
        if constexpr (BF32) hb[s][e] = (_Float16)BS[s][e];                    \
        else hb[s][e] = __builtin_bit_cast(_Float16, (u16)BS[s][e]);          \
      } }

#define PCOMPSTORE(TILE)                                                      \
  { f32x4 acc[13];                                                            \
    _Pragma("unroll")                                                         \
    for (int t = 0; t < 13; ++t)                                              \
      _Pragma("unroll")                                                       \
      for (int q = 0; q < 4; ++q) acc[t][q] = 0.f;                            \
    _Pragma("unroll")                                                         \
    for (int s = 0; s < 7; ++s) {                                             \
      _Pragma("unroll")                                                       \
      for (int t = 0; t < 13; ++t) {                                          \
        half8 ah = *(const half8*)(As + (t*16 + l15)*LSTR + (s*4 + kg)*8);    \
        acc[t] = __builtin_amdgcn_mfma_f32_16x16x32_f16(ah, hb[s], acc[t],    \
                                                        0, 0, 0);             \
      } }                                                                     \
    const int c0 = (TILE)*128 + wave*16;                                      \
    const int ai = c0 / NB;                                                   \
    const long db = (long)ai * bStrideD;                                      \
    const int nl = c0 - ai*NB + l15;                                          \
    _Pragma("unroll")                                                         \
    for (int t = 0; t < 13; ++t) {                                            \
      const int rb = t*16 + kg*4;                                             \
      _Pragma("unroll")                                                       \
      for (int r = 0; r < 4; ++r) {                                           \
        const int row = rb + r;                                               \
        if (row < N12)                                                        \
          Dout[db + (long)row * ldD + nl] =                                   \
              __builtin_bit_cast(u16, (_Float16)acc[t][r]);                   \
      } } }

template <typename BT, int NB>
__global__ __launch_bounds__(512, 2) void k_contract_persist(
    const BT* __restrict__ Bsrc, const u16* __restrict__ Ah,
    u16* __restrict__ Dout, int ldB, int ldD, long bStrideB, long bStrideD) {
  constexpr bool BF32 = std::is_same_v<BT, float>;
  __shared__ __align__(16) u16 As[APAD * LSTR];   // 96,512 B (<160K) 1 blk/CU
  const int tid  = threadIdx.x;
  const int lane = tid & 63;
  const int wave = tid >> 6;
  const int l15  = lane & 15;
  const int kg   = lane >> 4;
  const int kq   = kg * 8;

  // one-time A fill: 208 rows x 28 chunks (16B each)
  for (int u = tid; u < APAD * 28; u += 512) {
    int row = u / 28, c = u - row * 28;
    int4 v = *(const int4*)(Ah + row * KPAD + c * 8);
    *(int4*)(&As[row * LSTR + c * 8]) = v;
  }
  __syncthreads();   // the ONLY barrier

  using BReg = std::conditional_t<BF32, f32x8, ushort8>;
  BReg BA[7], BB[7];
  half8 hb[7];

  const int tile0 = blockIdx.x * 10;
  PLOAD(tile0, BA)
  for (int j = 0; j < 10; j += 2) {
    PLOAD(tile0 + j + 1, BB)
    PCVT(BA)                 // waits only the OLDER set; BB stays in flight
    PCOMPSTORE(tile0 + j)
    if (j + 2 < 10) PLOAD(tile0 + j + 2, BA)
    PCVT(BB)
    PCOMPSTORE(tile0 + j + 1)
  }
}

// ------- contract k + elementwise, MFMA form (fp16 T2 input) --------------
__global__ __launch_bounds__(256, 8) void k_contract_k_mfma(
    const u16* __restrict__ T2h, const float* __restrict__ TT,
    const u16* __restrict__ K3B, float* __restrict__ reg) {
  __shared__ __align__(16) u16 bs[K3B_HALVES];   // 8 KB
  const int tid  = threadIdx.x;
  {
    const int4* src = (const int4*)K3B;
    int4* dst = (int4*)bs;
    dst[tid] = src[tid];
    dst[tid + 256] = src[tid + 256];
  }
  const int lane = tid & 63;
  const int wave = tid >> 6;
  const int l15  = lane & 15;
  const int kg   = lane >> 4;
  const int ab   = blockIdx.x * 4 + wave;         // 0..39999
  const int base = ab * SKS;
  __syncthreads();

  half8 bf[2][4];
#pragma unroll
  for (int ks = 0; ks < 2; ++ks)
#pragma unroll
    for (int cs = 0; cs < 4; ++cs)
      bf[ks][cs] = *(const half8*)(bs + ((ks * 4 + cs) * 64 + lane) * 8);

  half8 af[2][2];
#pragma unroll
  for (int rt = 0; rt < 2; ++rt)
#pragma unroll
    for (int ks = 0; ks < 2; ++ks)
#pragma unroll
      for (int e = 0; e < 8; ++e) {
        int k = ks * 32 + kg * 8 + e; if (k > 49) k = 49;
        af[rt][ks][e] =
            __builtin_bit_cast(_Float16, T2h[base + k * R2 + rt * 16 + l15]);
      }

  f32x4 acc[2][4];
#pragma unroll
  for (int rt = 0; rt < 2; ++rt)
#pragma unroll
    for (int cs = 0; cs < 4; ++cs)
#pragma unroll
      for (int q = 0; q < 4; ++q) acc[rt][cs][q] = 0.f;

#pragma unroll
  for (int rt = 0; rt < 2; ++rt)
#pragma unroll
    for (int ks = 0; ks < 2; ++ks)
#pragma unroll
      for (int cs = 0; cs < 4; ++cs)
        acc[rt][cs] = __builtin_amdgcn_mfma_f32_16x16x32_f16(
            af[rt][ks], bf[ks][cs], acc[rt][cs], 0, 0, 0);

  // epilogue: both rt halves of each 128B line stored back-to-back (R10 fix)
#pragma unroll
  for (int cs = 0; cs < 4; ++cs) {
    const int c = cs * 16 + l15;
    if (c < N3) {
      const int o0 = base + c * R2 + kg * 4;
      f32x4 tv0 = *(const f32x4*)(TT + o0);
      f32x4 tv1 = *(const f32x4*)(TT + o0 + 16);
      f32x4 r0, r1;
#pragma unroll
      for (int q = 0; q < 4; ++q) {
        r0[q] = acc[0][cs][q] * tv0[q];
        r1[q] = acc[1][cs][q] * tv1[q];
      }
      *(f32x4*)(reg + o0) = r0;
      *(f32x4*)(reg + o0 + 16) = r1;
    }
  }
}

// ------------- gather: out[n,s] = sum_k K3[c,k] * T2[a,b,k,s]  (a,b,c < 50)
template <typename T>
__global__ __launch_bounds__(256) void k_gather(
    const T* T2, const float* __restrict__ K3,
    const int* __restrict__ idx, float* __restrict__ out) {
  int g = blockIdx.x * 256 + threadIdx.x;   // 3.2M threads exactly
  int n = g >> 5, s = g & 31;
  int a = idx[n * 3 + 0], b = idx[n * 3 + 1], c = idx[n * 3 + 2];
  const T* t2 = T2 + a * SJK + b * SKS + s;
  const float* k3r = K3 + c * N3;
  float acc = 0.f;
#pragma unroll
  for (int k = 0; k < N3; ++k) {
    float v;
    if constexpr (std::is_same_v<T, float>) v = t2[k * R2];
    else v = (float)__builtin_bit_cast(_Float16, t2[k * R2]);
    acc = fmaf(k3r[k], v, acc);
  }
  out[g] = acc;
}

// ---------------- fallback path helpers (unused when ws >= 128 MB) ---------
__global__ __launch_bounds__(256) void k_transpose(
    const float* __restrict__ K2, float* __restrict__ K2T) {
  int t = blockIdx.x * 256 + threadIdx.x;
  if (t < N12 * N12) {
    int i = t / N12, a = t % N12;
    K2T[t] = K2[a * N12 + i];
  }
}

__global__ __launch_bounds__(256) void k_fallback_ci(
    const float* __restrict__ TT, const float* __restrict__ K1T,
    float* __restrict__ T1) {
  const int m  = blockIdx.x * 256 + threadIdx.x;
  const int a0 = blockIdx.y * 50;
  float acc[50];
#pragma unroll
  for (int aa = 0; aa < 50; ++aa) acc[aa] = 0.f;
#pragma unroll 2
  for (int i = 0; i < N12; ++i) {
    float v = TT[i * SJK + m];
    const float* kr = K1T + i * N12 + a0;
#pragma unroll
    for (int aa = 0; aa < 50; ++aa) acc[aa] = fmaf(kr[aa], v, acc[aa]);
  }
#pragma unroll
  for (int aa = 0; aa < 50; ++aa) T1[(a0 + aa) * SJK + m] = acc[aa];
}

__global__ __launch_bounds__(256) void k_contract_j_inplace(
    float* T12, const float* __restrict__ K2T) {
  __shared__ float lds[N12 * 80];   // 64000 B
  const int a    = blockIdx.y;
  const int m0   = blockIdx.x * 80;
  const int base = a * SJK + m0;
  for (int t = threadIdx.x; t < N12 * 80; t += 256) {
    int j = t / 80, ml = t % 80;
    lds[t] = T12[base + j * SKS + ml];
  }
  __syncthreads();
  for (int o = threadIdx.x; o < N12 * 80; o += 256) {
    int b = o / 80, ml = o % 80;
    float acc = 0.f;
#pragma unroll 4
    for (int j = 0; j < N12; ++j)
      acc = fmaf(K2T[j * N12 + b], lds[j * 80 + ml], acc);
    T12[base + b * SKS + ml] = acc;
  }
}

__global__ __launch_bounds__(256) void k_contract_k_reg(
    const float* T2, const float* __restrict__ TT,
    const float* __restrict__ K3, float* reg) {
  const int t  = blockIdx.x * 256 + threadIdx.x;
  const int s  = t & 31;
  const int ab = t >> 5;
  const int base = ab * SKS + s;
  float v[N3];
#pragma unroll
  for (int k = 0; k < N3; ++k) v[k] = T2[base + k * R2];
  for (int c = 0; c < N3; ++c) {
    const float* k3r = K3 + c * N3;
    float a0 = 0.f, a1 = 0.f, a2 = 0.f, a3 = 0.f;
#pragma unroll
    for (int k = 0; k < 48; k += 4) {
      a0 = fmaf(k3r[k],     v[k],     a0);
      a1 = fmaf(k3r[k + 1], v[k + 1], a1);
      a2 = fmaf(k3r[k + 2], v[k + 2], a2);
      a3 = fmaf(k3r[k + 3], v[k + 3], a3);
    }
    a0 = fmaf(k3r[48], v[48], a0);
    a1 = fmaf(k3r[49], v[49], a1);
    const int o = base + c * R2;
    reg[o] = ((a0 + a1) + (a2 + a3)) * TT[o];
  }
}

extern "C" void kernel_launch(void* const* d_in, const int* in_sizes, int n_in,
                              void* d_out, int out_size, void* d_ws, size_t ws_size,
                              hipStream_t stream) {
  const float* TT  = (const float*)d_in[0];
  const float* K1  = (const float*)d_in[1];
  const float* K2  = (const float*)d_in[2];
  const float* K3  = (const float*)d_in[3];
  const int*   idx = (const int*)d_in[4];

  float* out = (float*)d_out;          // [0, 3.2M)
  float* reg = out + OUT_ELEMS;        // [3.2M, 67.2M) -- also T1h scratch
  // Prepped fp16 K matrices + K3B fragment pack live at the start of the out
  // region (dead before k_gather overwrites out).
  u16* kh = (u16*)d_out;
  const int matoff = APAD * KPAD;               // K2 offset within kh
  const u16* k3b = kh + 2 * matoff;             // K3B offset

  k_prep<<<dim3((2 * matoff + K3B_HALVES + 255) / 256), 256, 0, stream>>>(
      K1, K2, K3, kh);

  const size_t need = (size_t)NTOT * sizeof(u16);   // 128,000,000 B
  if (ws_size >= need) {
    u16* T1h = (u16*)reg;          // 128 MB in reg region (dead before ck)
    u16* T2h = (u16*)d_ws;         // 128 MB
    // contract i: T1h[a,m] = sum_i K1[a,i]*TT[i,m]
    k_contract_persist<float, SJK><<<dim3(250), 512, 0, stream>>>(
        TT, kh, T1h, SJK, SJK, 0L, 0L);
    // contract j (batched over a): T2h[a,b,m2] = sum_j K2[b,j]*T1h[a,j,m2]
    k_contract_persist<u16, SKS><<<dim3(250), 512, 0, stream>>>(
        T1h, kh + matoff, T2h, SKS, SKS, (long)SJK, (long)SJK);
    // contract k (writes reg fp32 over T1h region -- T1 dead; K3B still live)
    k_contract_k_mfma<<<dim3(40000 / 4), 256, 0, stream>>>(T2h, TT, k3b, reg);
    // gather last (clobbers kh/k3b region)
    k_gather<u16><<<dim3(OUT_ELEMS / 256), 256, 0, stream>>>(T2h, K3, idx, out);
  } else {
    // fp32 fallback (never taken on this harness: rounds 1-14 ran ws path)
    float* k1t = out;                       // scratch inside out region
    float* k2t = out + N12 * N12;
    k_transpose<<<dim3((N12 * N12 + 255) / 256), 256, 0, stream>>>(K1, k1t);
    k_transpose<<<dim3((N12 * N12 + 255) / 256), 256, 0, stream>>>(K2, k2t);
    k_fallback_ci<<<dim3(SJK / 256, 4), 256, 0, stream>>>(TT, k1t, reg);
    k_contract_j_inplace<<<dim3(20, N12), 256, 0, stream>>>(reg, k2t);
    k_gather<float><<<dim3(OUT_ELEMS / 256), 256, 0, stream>>>(reg, K3, idx, out);
    k_contract_k_reg<<<dim3(40000 * 32 / 256), 256, 0, stream>>>(reg, TT, K3, reg);
  }
}

// Round 16
// 375.138 us; speedup vs baseline: 2.2311x; 2.2311x over previous
//
#include <hip/hip_runtime.h>
#include <type_traits>

// Problem constants (from reference):
//   B=100000, R1=1, N1=200, N2=200, N3=50, R2=32
//   TT_core: (1,200,200,50,32) f32  = 64,000,000 elems (256 MB)
//   K1,K2: (200,200) f32; K3: (50,50) f32; indices: (B,3) int (values in [0,50))
//   out = (T3 gathered)[B,1,32] (3.2M f32), reg = T3*TT (64M f32)
// d_out layout: [0,3.2M) out, [3.2M, 67.2M) reg.
//
// Round-16: contiguous-B GEMM. R10-R15 invariant: ci/cj pinned at 160-175us
// across every LDS/barrier/occupancy structure; achieved BW ~1.7 TB/s on
// 256-384 MB = exactly 160us -> bound by DRAM segment granularity (64B/32B
// strided lane-loads), not by anything LDS-side. Now: B staged through LDS
// with 512B/256B contiguous row-segments (coalesced int4); T1 stored as
// [j][a*1600+m2] (permuted store) so cj has the same ldB=320000 contiguous
// rows as ci; 2-barrier/stage dbuf pipeline; bijective XCD swizzle (m204).

typedef float    f32x4 __attribute__((ext_vector_type(4)));
typedef _Float16 half8 __attribute__((ext_vector_type(8)));
typedef unsigned short ushort8 __attribute__((ext_vector_type(8)));
typedef unsigned short u16;
typedef unsigned int   u32;

#define N12   200
#define N3    50
#define R2    32
#define SJK   320000          // flat n per GEMM; also a-stride of [a][j][m2]
#define SKS   1600            // stride of j / b  == N3*R2
#define NTOT  64000000
#define OUT_ELEMS 3200000     // B*32
#define APAD  208             // padded rows of K matrices (13 * 16)
#define KPAD  224             // padded contraction dim (7 * 32)
#define BROW  136             // B LDS row stride in halves (272B, int4-aligned)
#define K3B_HALVES 4096       // 2 kstep * 4 csub * 64 lane * 8 e

// ---------------- prep: K1,K2 -> padded fp16 [208][224]; K3 -> B-frag pack --
__global__ __launch_bounds__(256) void k_prep(
    const float* __restrict__ K1, const float* __restrict__ K2,
    const float* __restrict__ K3, u16* __restrict__ kh) {
  int t = blockIdx.x * 256 + threadIdx.x;
  const int total = APAD * KPAD;
  if (t >= 2 * total + K3B_HALVES) return;
  float x;
  if (t < 2 * total) {
    const float* src = (t < total) ? K1 : K2;
    int tt = (t < total) ? t : t - total;
    int r = tt / KPAD, c = tt % KPAD;
    x = (r < N12 && c < N12) ? src[r * N12 + c] : 0.f;
  } else {
    int u = t - 2 * total;
    int e = u & 7, l = (u >> 3) & 63, frag = u >> 9;   // frag = kstep*4+csub
    int c = (frag & 3) * 16 + (l & 15);
    int k = (frag >> 2) * 32 + (l >> 4) * 8 + e;
    x = (c < N3 && k < N3) ? K3[c * N3 + k] : 0.f;
  }
  kh[t] = __builtin_bit_cast(u16, (_Float16)x);
}

// ------------- contiguous-B GEMM: D[row,n] = sum_k K[row,k] * B[k,n] -------
// B rows are contiguous (ldB = 320000). 512 thr / 8 waves, BN=128 per block.
// Per 32-k stage: B-tile [32][128] coop-loaded as 512B(ci)/256B(cj) row
// segments into LDS [32][BROW] u16 (cvt at stage for ci); A-slice [208][32]
// halves dbuf'd. 2 barriers/stage; next-stage global loads issued before
// compute (drains are BW-bound). Store permutes n=(j,m2) -> [j][row*1600+m2]
// so the consumer always sees [outer][inner] with contiguous k-rows.
template <typename BT>
__global__ __launch_bounds__(512, 4) void k_gemm(
    const BT* __restrict__ Bsrc, const u16* __restrict__ Ah,
    u16* __restrict__ Dout) {
  constexpr bool BF32 = std::is_same_v<BT, float>;
  __shared__ __align__(16) u16 As[2][APAD * 32];   // 2 x 13,312 B
  __shared__ __align__(16) u16 Bl[2][32 * BROW];   // 2 x 8,704 B
  const int tid  = threadIdx.x;
  const int lane = tid & 63;
  const int wave = tid >> 6;
  const int l15  = lane & 15;
  const int kg   = lane >> 4;
  // bijective XCD swizzle (m204): nwg=2500 = 8*312 + 4
  const int orig = blockIdx.x;
  const int xcd = orig & 7, pos = orig >> 3;
  const int blk = (xcd < 4 ? xcd * 313 : 4 * 313 + (xcd - 4) * 312) + pos;
  const int nblk = blk * 128;
  const int n0   = nblk + wave * 16 + l15;

  // fill-assignment constants
  const int arow0 = tid >> 2,  ac4 = tid & 3;            // u = tid      (<832)
  const int arow1 = (tid + 512) >> 2, ac4b = tid & 3;    // u = tid+512  (<832)
  const bool a1v  = tid < 320;
  const int brow  = tid >> 4,  bc8 = tid & 15;           // 32 rows x 16 chunks

  int4 ra0, ra1;
  f32x4 rb0, rb1;            // ci raw B (8 floats)
  ushort8 rbh;               // staged B halves (cj raw / ci post-cvt)

#define GLOAD(S)                                                              \
  { ra0 = *(const int4*)(Ah + arow0 * KPAD + (S) * 32 + ac4 * 8);             \
    if (a1v) ra1 = *(const int4*)(Ah + arow1 * KPAD + (S) * 32 + ac4b * 8);   \
    int r = (S) * 32 + brow; if (r > 199) r = 199;                            \
    if constexpr (BF32) {                                                     \
      const float* bp = (const float*)Bsrc + (long)r * SJK + nblk + bc8 * 8;  \
      rb0 = *(const f32x4*)bp; rb1 = *(const f32x4*)(bp + 4);                 \
    } else {                                                                  \
      rbh = *(const ushort8*)((const u16*)Bsrc + (long)r * SJK + nblk + bc8 * 8); \
    } }

#define DSWRITE(BUF)                                                          \
  { *(int4*)(&As[BUF][arow0 * 32 + ac4 * 8]) = ra0;                           \
    if (a1v) *(int4*)(&As[BUF][arow1 * 32 + ac4b * 8]) = ra1;                 \
    if constexpr (BF32) {                                                     \
      ushort8 h;                                                              \
      _Pragma("unroll")                                                       \
      for (int e = 0; e < 4; ++e) {                                           \
        h[e]     = __builtin_bit_cast(u16, (_Float16)rb0[e]);                 \
        h[e + 4] = __builtin_bit_cast(u16, (_Float16)rb1[e]);                 \
      }                                                                       \
      *(ushort8*)(&Bl[BUF][brow * BROW + bc8 * 8]) = h;                       \
    } else {                                                                  \
      *(ushort8*)(&Bl[BUF][brow * BROW + bc8 * 8]) = rbh;                     \
    } }

#define COMPUTE(BUF)                                                          \
  { half8 bh;                                                                 \
    _Pragma("unroll")                                                         \
    for (int e = 0; e < 8; ++e)                                               \
      bh[e] = __builtin_bit_cast(_Float16,                                    \
                  Bl[BUF][(kg * 8 + e) * BROW + wave * 16 + l15]);            \
    _Pragma("unroll")                                                         \
    for (int t = 0; t < 13; ++t) {                                            \
      half8 ah = *(const half8*)(&As[BUF][(t * 16 + l15) * 32 + kg * 8]);     \
      acc[t] = __builtin_amdgcn_mfma_f32_16x16x32_f16(ah, bh, acc[t], 0,0,0); \
    } }

  f32x4 acc[13];
#pragma unroll
  for (int t = 0; t < 13; ++t)
#pragma unroll
    for (int q = 0; q < 4; ++q) acc[t][q] = 0.f;

  GLOAD(0)
  DSWRITE(0)
  __syncthreads();
#pragma unroll
  for (int s = 0; s < 7; ++s) {
    if (s < 6) GLOAD(s + 1)
    COMPUTE(s & 1)
    __syncthreads();
    if (s < 6) {
      DSWRITE((s + 1) & 1)
      __syncthreads();
    }
  }

  // permuted store: n0 = (j, m2); D[j*320000 + row*1600 + m2]
  const int j  = (u32)n0 / 1600u;
  const int m2 = n0 - j * 1600;
  u16* dbase = Dout + (long)j * SJK + m2;
#pragma unroll
  for (int t = 0; t < 13; ++t) {
    const int rb = t * 16 + kg * 4;
#pragma unroll
    for (int r = 0; r < 4; ++r) {
      const int row = rb + r;
      if (row < N12)
        dbase[(long)row * SKS] = __builtin_bit_cast(u16, (_Float16)acc[t][r]);
      // note: dbase indexed per-row; lane m2 gives 32B-contiguous segments
    }
    // advance handled via row*SKS each iteration (compiler folds)
  }
#undef GLOAD
#undef DSWRITE
#undef COMPUTE
}

// ------- contract k + elementwise, MFMA form (fp16 T2 input) --------------
__global__ __launch_bounds__(256, 8) void k_contract_k_mfma(
    const u16* __restrict__ T2h, const float* __restrict__ TT,
    const u16* __restrict__ K3B, float* __restrict__ reg) {
  __shared__ __align__(16) u16 bs[K3B_HALVES];   // 8 KB
  const int tid  = threadIdx.x;
  {
    const int4* src = (const int4*)K3B;
    int4* dst = (int4*)bs;
    dst[tid] = src[tid];
    dst[tid + 256] = src[tid + 256];
  }
  const int lane = tid & 63;
  const int wave = tid >> 6;
  const int l15  = lane & 15;
  const int kg   = lane >> 4;
  const int ab   = blockIdx.x * 4 + wave;         // 0..39999
  const int base = ab * SKS;
  __syncthreads();

  half8 bf[2][4];
#pragma unroll
  for (int ks = 0; ks < 2; ++ks)
#pragma unroll
    for (int cs = 0; cs < 4; ++cs)
      bf[ks][cs] = *(const half8*)(bs + ((ks * 4 + cs) * 64 + lane) * 8);

  half8 af[2][2];
#pragma unroll
  for (int rt = 0; rt < 2; ++rt)
#pragma unroll
    for (int ks = 0; ks < 2; ++ks)
#pragma unroll
      for (int e = 0; e < 8; ++e) {
        int k = ks * 32 + kg * 8 + e; if (k > 49) k = 49;
        af[rt][ks][e] =
            __builtin_bit_cast(_Float16, T2h[base + k * R2 + rt * 16 + l15]);
      }

  f32x4 acc[2][4];
#pragma unroll
  for (int rt = 0; rt < 2; ++rt)
#pragma unroll
    for (int cs = 0; cs < 4; ++cs)
#pragma unroll
      for (int q = 0; q < 4; ++q) acc[rt][cs][q] = 0.f;

#pragma unroll
  for (int rt = 0; rt < 2; ++rt)
#pragma unroll
    for (int ks = 0; ks < 2; ++ks)
#pragma unroll
      for (int cs = 0; cs < 4; ++cs)
        acc[rt][cs] = __builtin_amdgcn_mfma_f32_16x16x32_f16(
            af[rt][ks], bf[ks][cs], acc[rt][cs], 0, 0, 0);

  // epilogue: both rt halves of each 128B line stored back-to-back (R10 fix)
#pragma unroll
  for (int cs = 0; cs < 4; ++cs) {
    const int c = cs * 16 + l15;
    if (c < N3) {
      const int o0 = base + c * R2 + kg * 4;
      f32x4 tv0 = *(const f32x4*)(TT + o0);
      f32x4 tv1 = *(const f32x4*)(TT + o0 + 16);
      f32x4 r0, r1;
#pragma unroll
      for (int q = 0; q < 4; ++q) {
        r0[q] = acc[0][cs][q] * tv0[q];
        r1[q] = acc[1][cs][q] * tv1[q];
      }
      *(f32x4*)(reg + o0) = r0;
      *(f32x4*)(reg + o0 + 16) = r1;
    }
  }
}

// ------------- gather: out[n,s] = sum_k K3[c,k] * T2[a,b,k,s]  (a,b,c < 50)
template <typename T>
__global__ __launch_bounds__(256) void k_gather(
    const T* T2, const float* __restrict__ K3,
    const int* __restrict__ idx, float* __restrict__ out) {
  int g = blockIdx.x * 256 + threadIdx.x;   // 3.2M threads exactly
  int n = g >> 5, s = g & 31;
  int a = idx[n * 3 + 0], b = idx[n * 3 + 1], c = idx[n * 3 + 2];
  const T* t2 = T2 + a * SJK + b * SKS + s;
  const float* k3r = K3 + c * N3;
  float acc = 0.f;
#pragma unroll
  for (int k = 0; k < N3; ++k) {
    float v;
    if constexpr (std::is_same_v<T, float>) v = t2[k * R2];
    else v = (float)__builtin_bit_cast(_Float16, t2[k * R2]);
    acc = fmaf(k3r[k], v, acc);
  }
  out[g] = acc;
}

// ---------------- fallback path helpers (unused when ws >= 128 MB) ---------
__global__ __launch_bounds__(256) void k_transpose(
    const float* __restrict__ K2, float* __restrict__ K2T) {
  int t = blockIdx.x * 256 + threadIdx.x;
  if (t < N12 * N12) {
    int i = t / N12, a = t % N12;
    K2T[t] = K2[a * N12 + i];
  }
}

__global__ __launch_bounds__(256) void k_fallback_ci(
    const float* __restrict__ TT, const float* __restrict__ K1T,
    float* __restrict__ T1) {
  const int m  = blockIdx.x * 256 + threadIdx.x;
  const int a0 = blockIdx.y * 50;
  float acc[50];
#pragma unroll
  for (int aa = 0; aa < 50; ++aa) acc[aa] = 0.f;
#pragma unroll 2
  for (int i = 0; i < N12; ++i) {
    float v = TT[i * SJK + m];
    const float* kr = K1T + i * N12 + a0;
#pragma unroll
    for (int aa = 0; aa < 50; ++aa) acc[aa] = fmaf(kr[aa], v, acc[aa]);
  }
#pragma unroll
  for (int aa = 0; aa < 50; ++aa) T1[(a0 + aa) * SJK + m] = acc[aa];
}

__global__ __launch_bounds__(256) void k_contract_j_inplace(
    float* T12, const float* __restrict__ K2T) {
  __shared__ float lds[N12 * 80];   // 64000 B
  const int a    = blockIdx.y;
  const int m0   = blockIdx.x * 80;
  const int base = a * SJK + m0;
  for (int t = threadIdx.x; t < N12 * 80; t += 256) {
    int j = t / 80, ml = t % 80;
    lds[t] = T12[base + j * SKS + ml];
  }
  __syncthreads();
  for (int o = threadIdx.x; o < N12 * 80; o += 256) {
    int b = o / 80, ml = o % 80;
    float acc = 0.f;
#pragma unroll 4
    for (int j = 0; j < N12; ++j)
      acc = fmaf(K2T[j * N12 + b], lds[j * 80 + ml], acc);
    T12[base + b * SKS + ml] = acc;
  }
}

__global__ __launch_bounds__(256) void k_contract_k_reg(
    const float* T2, const float* __restrict__ TT,
    const float* __restrict__ K3, float* reg) {
  const int t  = blockIdx.x * 256 + threadIdx.x;
  const int s  = t & 31;
  const int ab = t >> 5;
  const int base = ab * SKS + s;
  float v[N3];
#pragma unroll
  for (int k = 0; k < N3; ++k) v[k] = T2[base + k * R2];
  for (int c = 0; c < N3; ++c) {
    const float* k3r = K3 + c * N3;
    float a0 = 0.f, a1 = 0.f, a2 = 0.f, a3 = 0.f;
#pragma unroll
    for (int k = 0; k < 48; k += 4) {
      a0 = fmaf(k3r[k],     v[k],     a0);
      a1 = fmaf(k3r[k + 1], v[k + 1], a1);
      a2 = fmaf(k3r[k + 2], v[k + 2], a2);
      a3 = fmaf(k3r[k + 3], v[k + 3], a3);
    }
    a0 = fmaf(k3r[48], v[48], a0);
    a1 = fmaf(k3r[49], v[49], a1);
    const int o = base + c * R2;
    reg[o] = ((a0 + a1) + (a2 + a3)) * TT[o];
  }
}

extern "C" void kernel_launch(void* const* d_in, const int* in_sizes, int n_in,
                              void* d_out, int out_size, void* d_ws, size_t ws_size,
                              hipStream_t stream) {
  const float* TT  = (const float*)d_in[0];
  const float* K1  = (const float*)d_in[1];
  const float* K2  = (const float*)d_in[2];
  const float* K3  = (const float*)d_in[3];
  const int*   idx = (const int*)d_in[4];

  float* out = (float*)d_out;          // [0, 3.2M)
  float* reg = out + OUT_ELEMS;        // [3.2M, 67.2M) -- also T1h scratch
  // Prepped fp16 K matrices + K3B fragment pack live at the start of the out
  // region (dead before k_gather overwrites out).
  u16* kh = (u16*)d_out;
  const int matoff = APAD * KPAD;               // K2 offset within kh
  const u16* k3b = kh + 2 * matoff;             // K3B offset

  k_prep<<<dim3((2 * matoff + K3B_HALVES + 255) / 256), 256, 0, stream>>>(
      K1, K2, K3, kh);

  const size_t need = (size_t)NTOT * sizeof(u16);   // 128,000,000 B
  if (ws_size >= need) {
    u16* T1h = (u16*)reg;          // 128 MB in reg region (dead before ck)
    u16* T2h = (u16*)d_ws;         // 128 MB
    // contract i: T1h stored PERMUTED as [j][a*1600+m2]
    k_gemm<float><<<dim3(2500), 512, 0, stream>>>(TT, kh, T1h);
    // contract j: reads T1h rows contiguously; T2h stored as [a][b*1600+m2]
    k_gemm<u16><<<dim3(2500), 512, 0, stream>>>(T1h, kh + matoff, T2h);
    // contract k (writes reg fp32 over T1h region -- T1 dead; K3B still live)
    k_contract_k_mfma<<<dim3(40000 / 4), 256, 0, stream>>>(T2h, TT, k3b, reg);
    // gather last (clobbers kh/k3b region)
    k_gather<u16><<<dim3(OUT_ELEMS / 256), 256, 0, stream>>>(T2h, K3, idx, out);
  } else {
    // fp32 fallback (never taken on this harness: rounds 1-15 ran ws path)
    float* k1t = out;                       // scratch inside out region
    float* k2t = out + N12 * N12;
    k_transpose<<<dim3((N12 * N12 + 255) / 256), 256, 0, stream>>>(K1, k1t);
    k_transpose<<<dim3((N12 * N12 + 255) / 256), 256, 0, stream>>>(K2, k2t);
    k_fallback_ci<<<dim3(SJK / 256, 4), 256, 0, stream>>>(TT, k1t, reg);
    k_contract_j_inplace<<<dim3(20, N12), 256, 0, stream>>>(reg, k2t);
    k_gather<float><<<dim3(OUT_ELEMS / 256), 256, 0, stream>>>(reg, K3, idx, out);
    k_contract_k_reg<<<dim3(40000 * 32 / 256), 256, 0, stream>>>(reg, TT, K3, reg);
  }
}

// Round 17
// 342.513 us; speedup vs baseline: 2.4436x; 1.0953x over previous
//
#include <hip/hip_runtime.h>
#include <type_traits>

// Problem constants (from reference):
//   B=100000, R1=1, N1=200, N2=200, N3=50, R2=32
//   TT_core: (1,200,200,50,32) f32  = 64,000,000 elems (256 MB)
//   K1,K2: (200,200) f32; K3: (50,50) f32; indices: (B,3) int (values in [0,50))
//   out = (T3 gathered)[B,1,32] (3.2M f32), reg = T3*TT (64M f32)
// d_out layout: [0,3.2M) out, [3.2M, 67.2M) reg.
//
// Round-17: ck A-load vectorization. R16 evidence: ck leads at 154us, HBM 48%,
// VALU 5% -- its A-fragments were 32 scalar u16 loads/wave (stride-64B, 128B
// payload per instr). The per-wave T2h slab is 3.2KB CONTIGUOUS: now loaded
// as 4 coalesced ushort8/lane (1KB/instr), scattered into a per-wave
// transposed LDS slab [s][64] (XOR swizzle phys_k = k ^ ((s&7)<<3), keeps
// e-runs contiguous + 16B aligned), A-fragments = 4 ds_read_b128. Slab
// zero-filled (pad k>=50 rows contribute 0 via zero, not NaN). Wave-private
// slab -> no barrier (same-wave DS ops are in-order). ci/cj (R16 contiguous-B
// GEMM) unchanged.

typedef float    f32x4 __attribute__((ext_vector_type(4)));
typedef _Float16 half8 __attribute__((ext_vector_type(8)));
typedef unsigned short ushort8 __attribute__((ext_vector_type(8)));
typedef unsigned short u16;
typedef unsigned int   u32;

#define N12   200
#define N3    50
#define R2    32
#define SJK   320000          // flat n per GEMM; also a-stride of [a][j][m2]
#define SKS   1600            // stride of j / b  == N3*R2
#define NTOT  64000000
#define OUT_ELEMS 3200000     // B*32
#define APAD  208             // padded rows of K matrices (13 * 16)
#define KPAD  224             // padded contraction dim (7 * 32)
#define BROW  136             // B LDS row stride in halves (272B, int4-aligned)
#define K3B_HALVES 4096       // 2 kstep * 4 csub * 64 lane * 8 e

// ---------------- prep: K1,K2 -> padded fp16 [208][224]; K3 -> B-frag pack --
__global__ __launch_bounds__(256) void k_prep(
    const float* __restrict__ K1, const float* __restrict__ K2,
    const float* __restrict__ K3, u16* __restrict__ kh) {
  int t = blockIdx.x * 256 + threadIdx.x;
  const int total = APAD * KPAD;
  if (t >= 2 * total + K3B_HALVES) return;
  float x;
  if (t < 2 * total) {
    const float* src = (t < total) ? K1 : K2;
    int tt = (t < total) ? t : t - total;
    int r = tt / KPAD, c = tt % KPAD;
    x = (r < N12 && c < N12) ? src[r * N12 + c] : 0.f;
  } else {
    int u = t - 2 * total;
    int e = u & 7, l = (u >> 3) & 63, frag = u >> 9;   // frag = kstep*4+csub
    int c = (frag & 3) * 16 + (l & 15);
    int k = (frag >> 2) * 32 + (l >> 4) * 8 + e;
    x = (c < N3 && k < N3) ? K3[c * N3 + k] : 0.f;
  }
  kh[t] = __builtin_bit_cast(u16, (_Float16)x);
}

// ------------- contiguous-B GEMM: D[row,n] = sum_k K[row,k] * B[k,n] -------
// (unchanged from round 16 -- see notes there)
template <typename BT>
__global__ __launch_bounds__(512, 4) void k_gemm(
    const BT* __restrict__ Bsrc, const u16* __restrict__ Ah,
    u16* __restrict__ Dout) {
  constexpr bool BF32 = std::is_same_v<BT, float>;
  __shared__ __align__(16) u16 As[2][APAD * 32];   // 2 x 13,312 B
  __shared__ __align__(16) u16 Bl[2][32 * BROW];   // 2 x 8,704 B
  const int tid  = threadIdx.x;
  const int lane = tid & 63;
  const int wave = tid >> 6;
  const int l15  = lane & 15;
  const int kg   = lane >> 4;
  // bijective XCD swizzle (m204): nwg=2500 = 8*312 + 4
  const int orig = blockIdx.x;
  const int xcd = orig & 7, pos = orig >> 3;
  const int blk = (xcd < 4 ? xcd * 313 : 4 * 313 + (xcd - 4) * 312) + pos;
  const int nblk = blk * 128;
  const int n0   = nblk + wave * 16 + l15;

  const int arow0 = tid >> 2,  ac4 = tid & 3;            // u = tid      (<832)
  const int arow1 = (tid + 512) >> 2, ac4b = tid & 3;    // u = tid+512  (<832)
  const bool a1v  = tid < 320;
  const int brow  = tid >> 4,  bc8 = tid & 15;           // 32 rows x 16 chunks

  int4 ra0, ra1;
  f32x4 rb0, rb1;            // ci raw B (8 floats)
  ushort8 rbh;               // cj raw B halves

#define GLOAD(S)                                                              \
  { ra0 = *(const int4*)(Ah + arow0 * KPAD + (S) * 32 + ac4 * 8);             \
    if (a1v) ra1 = *(const int4*)(Ah + arow1 * KPAD + (S) * 32 + ac4b * 8);   \
    int r = (S) * 32 + brow; if (r > 199) r = 199;                            \
    if constexpr (BF32) {                                                     \
      const float* bp = (const float*)Bsrc + (long)r * SJK + nblk + bc8 * 8;  \
      rb0 = *(const f32x4*)bp; rb1 = *(const f32x4*)(bp + 4);                 \
    } else {                                                                  \
      rbh = *(const ushort8*)((const u16*)Bsrc + (long)r * SJK + nblk + bc8 * 8); \
    } }

#define DSWRITE(BUF)                                                          \
  { *(int4*)(&As[BUF][arow0 * 32 + ac4 * 8]) = ra0;                           \
    if (a1v) *(int4*)(&As[BUF][arow1 * 32 + ac4b * 8]) = ra1;                 \
    if constexpr (BF32) {                                                     \
      ushort8 h;                                                              \
      _Pragma("unroll")                                                       \
      for (int e = 0; e < 4; ++e) {                                           \
        h[e]     = __builtin_bit_cast(u16, (_Float16)rb0[e]);                 \
        h[e + 4] = __builtin_bit_cast(u16, (_Float16)rb1[e]);                 \
      }                                                                       \
      *(ushort8*)(&Bl[BUF][brow * BROW + bc8 * 8]) = h;                       \
    } else {                                                                  \
      *(ushort8*)(&Bl[BUF][brow * BROW + bc8 * 8]) = rbh;                     \
    } }

#define COMPUTE(BUF)                                                          \
  { half8 bh;                                                                 \
    _Pragma("unroll")                                                         \
    for (int e = 0; e < 8; ++e)                                               \
      bh[e] = __builtin_bit_cast(_Float16,                                    \
                  Bl[BUF][(kg * 8 + e) * BROW + wave * 16 + l15]);            \
    _Pragma("unroll")                                                         \
    for (int t = 0; t < 13; ++t) {                                            \
      half8 ah = *(const half8*)(&As[BUF][(t * 16 + l15) * 32 + kg * 8]);     \
      acc[t] = __builtin_amdgcn_mfma_f32_16x16x32_f16(ah, bh, acc[t], 0,0,0); \
    } }

  f32x4 acc[13];
#pragma unroll
  for (int t = 0; t < 13; ++t)
#pragma unroll
    for (int q = 0; q < 4; ++q) acc[t][q] = 0.f;

  GLOAD(0)
  DSWRITE(0)
  __syncthreads();
#pragma unroll
  for (int s = 0; s < 7; ++s) {
    if (s < 6) GLOAD(s + 1)
    COMPUTE(s & 1)
    __syncthreads();
    if (s < 6) {
      DSWRITE((s + 1) & 1)
      __syncthreads();
    }
  }

  // permuted store: n0 = (j, m2); D[j*320000 + row*1600 + m2]
  const int j  = (u32)n0 / 1600u;
  const int m2 = n0 - j * 1600;
  u16* dbase = Dout + (long)j * SJK + m2;
#pragma unroll
  for (int t = 0; t < 13; ++t) {
    const int rb = t * 16 + kg * 4;
#pragma unroll
    for (int r = 0; r < 4; ++r) {
      const int row = rb + r;
      if (row < N12)
        dbase[(long)row * SKS] = __builtin_bit_cast(u16, (_Float16)acc[t][r]);
    }
  }
#undef GLOAD
#undef DSWRITE
#undef COMPUTE
}

// ------- contract k + elementwise, MFMA form (fp16 T2 input) --------------
// Per wave: one ab. D[s,c] = sum_k T2[ab,k,s]*K3[c,k]; B = K3B frags (LDS).
// A path (R17): slab loaded as 4 contiguous ushort8/lane, scattered to a
// wave-private transposed LDS slab [s][64] with phys_k = k ^ ((s&7)<<3);
// fragments read back as aligned ds_read_b128. Pad rows zeroed.
__global__ __launch_bounds__(256, 4) void k_contract_k_mfma(
    const u16* __restrict__ T2h, const float* __restrict__ TT,
    const u16* __restrict__ K3B, float* __restrict__ reg) {
  __shared__ __align__(16) u16 bs[K3B_HALVES];   // 8 KB
  __shared__ __align__(16) u16 sl[4][32 * 64];   // 4 x 4 KB per-wave slabs
  const int tid  = threadIdx.x;
  {
    const int4* src = (const int4*)K3B;
    int4* dst = (int4*)bs;
    dst[tid] = src[tid];
    dst[tid + 256] = src[tid + 256];
  }
  const int lane = tid & 63;
  const int wave = tid >> 6;
  const int l15  = lane & 15;
  const int kg   = lane >> 4;
  const int ab   = blockIdx.x * 4 + wave;         // 0..39999
  const int base = ab * SKS;
  u16* s_ = &sl[wave][0];

  // zero the slab (pad k=50..63 must be 0.0, not garbage-NaN)
  {
    ushort8 z;
#pragma unroll
    for (int e = 0; e < 8; ++e) z[e] = 0;
#pragma unroll
    for (int c = 0; c < 4; ++c)
      *(ushort8*)(&s_[(c * 64 + lane) * 8]) = z;
  }
  // contiguous slab load + transposed swizzled scatter (wave-private; DS ops
  // from one wave execute in order -> no barrier needed)
#pragma unroll
  for (int c = 0; c < 4; ++c) {
    const int ch = c * 64 + lane;                 // 16B chunk id, 200 valid
    if (ch < 200) {
      ushort8 v = *(const ushort8*)(T2h + base + ch * 8);
      const int k  = ch >> 2;                     // 0..49
      const int s0 = (ch & 3) * 8;                // 0,8,16,24
#pragma unroll
      for (int j = 0; j < 8; ++j)
        s_[(s0 + j) * 64 + (k ^ (j << 3))] = v[j];   // (s0+j)&7 == j
    }
  }
  __syncthreads();                                // bs ready

  half8 bf[2][4];
#pragma unroll
  for (int ks = 0; ks < 2; ++ks)
#pragma unroll
    for (int cs = 0; cs < 4; ++cs)
      bf[ks][cs] = *(const half8*)(bs + ((ks * 4 + cs) * 64 + lane) * 8);

  // A fragments from the transposed slab: s = rt*16+l15, k-run = ks*32+kg*8+e
  half8 af[2][2];
#pragma unroll
  for (int rt = 0; rt < 2; ++rt)
#pragma unroll
    for (int ks = 0; ks < 2; ++ks) {
      const int s = rt * 16 + l15;
      af[rt][ks] = *(const half8*)(
          &s_[s * 64 + ((ks * 32 + kg * 8) ^ ((s & 7) << 3))]);
    }

  f32x4 acc[2][4];
#pragma unroll
  for (int rt = 0; rt < 2; ++rt)
#pragma unroll
    for (int cs = 0; cs < 4; ++cs)
#pragma unroll
      for (int q = 0; q < 4; ++q) acc[rt][cs][q] = 0.f;

#pragma unroll
  for (int rt = 0; rt < 2; ++rt)
#pragma unroll
    for (int ks = 0; ks < 2; ++ks)
#pragma unroll
      for (int cs = 0; cs < 4; ++cs)
        acc[rt][cs] = __builtin_amdgcn_mfma_f32_16x16x32_f16(
            af[rt][ks], bf[ks][cs], acc[rt][cs], 0, 0, 0);

  // epilogue: both rt halves of each 128B line stored back-to-back (R10 fix)
#pragma unroll
  for (int cs = 0; cs < 4; ++cs) {
    const int c = cs * 16 + l15;
    if (c < N3) {
      const int o0 = base + c * R2 + kg * 4;
      f32x4 tv0 = *(const f32x4*)(TT + o0);
      f32x4 tv1 = *(const f32x4*)(TT + o0 + 16);
      f32x4 r0, r1;
#pragma unroll
      for (int q = 0; q < 4; ++q) {
        r0[q] = acc[0][cs][q] * tv0[q];
        r1[q] = acc[1][cs][q] * tv1[q];
      }
      *(f32x4*)(reg + o0) = r0;
      *(f32x4*)(reg + o0 + 16) = r1;
    }
  }
}

// ------------- gather: out[n,s] = sum_k K3[c,k] * T2[a,b,k,s]  (a,b,c < 50)
template <typename T>
__global__ __launch_bounds__(256) void k_gather(
    const T* T2, const float* __restrict__ K3,
    const int* __restrict__ idx, float* __restrict__ out) {
  int g = blockIdx.x * 256 + threadIdx.x;   // 3.2M threads exactly
  int n = g >> 5, s = g & 31;
  int a = idx[n * 3 + 0], b = idx[n * 3 + 1], c = idx[n * 3 + 2];
  const T* t2 = T2 + a * SJK + b * SKS + s;
  const float* k3r = K3 + c * N3;
  float acc = 0.f;
#pragma unroll
  for (int k = 0; k < N3; ++k) {
    float v;
    if constexpr (std::is_same_v<T, float>) v = t2[k * R2];
    else v = (float)__builtin_bit_cast(_Float16, t2[k * R2]);
    acc = fmaf(k3r[k], v, acc);
  }
  out[g] = acc;
}

// ---------------- fallback path helpers (unused when ws >= 128 MB) ---------
__global__ __launch_bounds__(256) void k_transpose(
    const float* __restrict__ K2, float* __restrict__ K2T) {
  int t = blockIdx.x * 256 + threadIdx.x;
  if (t < N12 * N12) {
    int i = t / N12, a = t % N12;
    K2T[t] = K2[a * N12 + i];
  }
}

__global__ __launch_bounds__(256) void k_fallback_ci(
    const float* __restrict__ TT, const float* __restrict__ K1T,
    float* __restrict__ T1) {
  const int m  = blockIdx.x * 256 + threadIdx.x;
  const int a0 = blockIdx.y * 50;
  float acc[50];
#pragma unroll
  for (int aa = 0; aa < 50; ++aa) acc[aa] = 0.f;
#pragma unroll 2
  for (int i = 0; i < N12; ++i) {
    float v = TT[i * SJK + m];
    const float* kr = K1T + i * N12 + a0;
#pragma unroll
    for (int aa = 0; aa < 50; ++aa) acc[aa] = fmaf(kr[aa], v, acc[aa]);
  }
#pragma unroll
  for (int aa = 0; aa < 50; ++aa) T1[(a0 + aa) * SJK + m] = acc[aa];
}

__global__ __launch_bounds__(256) void k_contract_j_inplace(
    float* T12, const float* __restrict__ K2T) {
  __shared__ float lds[N12 * 80];   // 64000 B
  const int a    = blockIdx.y;
  const int m0   = blockIdx.x * 80;
  const int base = a * SJK + m0;
  for (int t = threadIdx.x; t < N12 * 80; t += 256) {
    int j = t / 80, ml = t % 80;
    lds[t] = T12[base + j * SKS + ml];
  }
  __syncthreads();
  for (int o = threadIdx.x; o < N12 * 80; o += 256) {
    int b = o / 80, ml = o % 80;
    float acc = 0.f;
#pragma unroll 4
    for (int j = 0; j < N12; ++j)
      acc = fmaf(K2T[j * N12 + b], lds[j * 80 + ml], acc);
    T12[base + b * SKS + ml] = acc;
  }
}

__global__ __launch_bounds__(256) void k_contract_k_reg(
    const float* T2, const float* __restrict__ TT,
    const float* __restrict__ K3, float* reg) {
  const int t  = blockIdx.x * 256 + threadIdx.x;
  const int s  = t & 31;
  const int ab = t >> 5;
  const int base = ab * SKS + s;
  float v[N3];
#pragma unroll
  for (int k = 0; k < N3; ++k) v[k] = T2[base + k * R2];
  for (int c = 0; c < N3; ++c) {
    const float* k3r = K3 + c * N3;
    float a0 = 0.f, a1 = 0.f, a2 = 0.f, a3 = 0.f;
#pragma unroll
    for (int k = 0; k < 48; k += 4) {
      a0 = fmaf(k3r[k],     v[k],     a0);
      a1 = fmaf(k3r[k + 1], v[k + 1], a1);
      a2 = fmaf(k3r[k + 2], v[k + 2], a2);
      a3 = fmaf(k3r[k + 3], v[k + 3], a3);
    }
    a0 = fmaf(k3r[48], v[48], a0);
    a1 = fmaf(k3r[49], v[49], a1);
    const int o = base + c * R2;
    reg[o] = ((a0 + a1) + (a2 + a3)) * TT[o];
  }
}

extern "C" void kernel_launch(void* const* d_in, const int* in_sizes, int n_in,
                              void* d_out, int out_size, void* d_ws, size_t ws_size,
                              hipStream_t stream) {
  const float* TT  = (const float*)d_in[0];
  const float* K1  = (const float*)d_in[1];
  const float* K2  = (const float*)d_in[2];
  const float* K3  = (const float*)d_in[3];
  const int*   idx = (const int*)d_in[4];

  float* out = (float*)d_out;          // [0, 3.2M)
  float* reg = out + OUT_ELEMS;        // [3.2M, 67.2M) -- also T1h scratch
  // Prepped fp16 K matrices + K3B fragment pack live at the start of the out
  // region (dead before k_gather overwrites out).
  u16* kh = (u16*)d_out;
  const int matoff = APAD * KPAD;               // K2 offset within kh
  const u16* k3b = kh + 2 * matoff;             // K3B offset

  k_prep<<<dim3((2 * matoff + K3B_HALVES + 255) / 256), 256, 0, stream>>>(
      K1, K2, K3, kh);

  const size_t need = (size_t)NTOT * sizeof(u16);   // 128,000,000 B
  if (ws_size >= need) {
    u16* T1h = (u16*)reg;          // 128 MB in reg region (dead before ck)
    u16* T2h = (u16*)d_ws;         // 128 MB
    // contract i: T1h stored PERMUTED as [j][a*1600+m2]
    k_gemm<float><<<dim3(2500), 512, 0, stream>>>(TT, kh, T1h);
    // contract j: reads T1h rows contiguously; T2h stored as [a][b*1600+m2]
    k_gemm<u16><<<dim3(2500), 512, 0, stream>>>(T1h, kh + matoff, T2h);
    // contract k (writes reg fp32 over T1h region -- T1 dead; K3B still live)
    k_contract_k_mfma<<<dim3(40000 / 4), 256, 0, stream>>>(T2h, TT, k3b, reg);
    // gather last (clobbers kh/k3b region)
    k_gather<u16><<<dim3(OUT_ELEMS / 256), 256, 0, stream>>>(T2h, K3, idx, out);
  } else {
    // fp32 fallback (never taken on this harness: rounds 1-16 ran ws path)
    float* k1t = out;                       // scratch inside out region
    float* k2t = out + N12 * N12;
    k_transpose<<<dim3((N12 * N12 + 255) / 256), 256, 0, stream>>>(K1, k1t);
    k_transpose<<<dim3((N12 * N12 + 255) / 256), 256, 0, stream>>>(K2, k2t);
    k_fallback_ci<<<dim3(SJK / 256, 4), 256, 0, stream>>>(TT, k1t, reg);
    k_contract_j_inplace<<<dim3(20, N12), 256, 0, stream>>>(reg, k2t);
    k_gather<float><<<dim3(OUT_ELEMS / 256), 256, 0, stream>>>(reg, K3, idx, out);
    k_contract_k_reg<<<dim3(40000 * 32 / 256), 256, 0, stream>>>(reg, TT, K3, reg);
  }
}

// Round 18
// 339.657 us; speedup vs baseline: 2.4641x; 1.0084x over previous
//
#include <hip/hip_runtime.h>
#include <type_traits>

// Problem constants (from reference):
//   B=100000, R1=1, N1=200, N2=200, N3=50, R2=32
//   TT_core: (1,200,200,50,32) f32  = 64,000,000 elems (256 MB)
//   K1,K2: (200,200) f32; K3: (50,50) f32; indices: (B,3) int (values in [0,50))
//   out = (T3 gathered)[B,1,32] (3.2M f32), reg = T3*TT (64M f32)
// d_out layout: [0,3.2M) out, [3.2M, 67.2M) reg.
//
// Round-18: (1) k_gemm single-barrier-per-stage (T3 2-phase recipe; the
// mid-stage barrier was redundant -- DSWRITE targets the opposite dbuf from
// COMPUTE, prior readers separated by the previous barrier); (2) gather
// 2-wide (ushort2 loads, float2 store, half the threads); (3) ck occupancy
// 4->6 waves/EU. R17 evidence: all kernels < 152us (below harness fills);
// est. ci+cj+gather ~221us vs ~115us floor -- barrier structure is the
// remaining k_gemm slack (m233/T3: counted-stall amortization).

typedef float    f32x4 __attribute__((ext_vector_type(4)));
typedef _Float16 half8 __attribute__((ext_vector_type(8)));
typedef unsigned short ushort8 __attribute__((ext_vector_type(8)));
typedef unsigned short u16;
typedef unsigned int   u32;

#define N12   200
#define N3    50
#define R2    32
#define SJK   320000          // flat n per GEMM; also a-stride of [a][j][m2]
#define SKS   1600            // stride of j / b  == N3*R2
#define NTOT  64000000
#define OUT_ELEMS 3200000     // B*32
#define APAD  208             // padded rows of K matrices (13 * 16)
#define KPAD  224             // padded contraction dim (7 * 32)
#define BROW  136             // B LDS row stride in halves (272B, int4-aligned)
#define K3B_HALVES 4096       // 2 kstep * 4 csub * 64 lane * 8 e

// ---------------- prep: K1,K2 -> padded fp16 [208][224]; K3 -> B-frag pack --
__global__ __launch_bounds__(256) void k_prep(
    const float* __restrict__ K1, const float* __restrict__ K2,
    const float* __restrict__ K3, u16* __restrict__ kh) {
  int t = blockIdx.x * 256 + threadIdx.x;
  const int total = APAD * KPAD;
  if (t >= 2 * total + K3B_HALVES) return;
  float x;
  if (t < 2 * total) {
    const float* src = (t < total) ? K1 : K2;
    int tt = (t < total) ? t : t - total;
    int r = tt / KPAD, c = tt % KPAD;
    x = (r < N12 && c < N12) ? src[r * N12 + c] : 0.f;
  } else {
    int u = t - 2 * total;
    int e = u & 7, l = (u >> 3) & 63, frag = u >> 9;   // frag = kstep*4+csub
    int c = (frag & 3) * 16 + (l & 15);
    int k = (frag >> 2) * 32 + (l >> 4) * 8 + e;
    x = (c < N3 && k < N3) ? K3[c * N3 + k] : 0.f;
  }
  kh[t] = __builtin_bit_cast(u16, (_Float16)x);
}

// ------------- contiguous-B GEMM: D[row,n] = sum_k K[row,k] * B[k,n] -------
// B rows contiguous (ldB = 320000); B-tile [32][128] coop-loaded as 512B/256B
// row segments; A-slice [208][32] dbuf'd. R18: ONE barrier per stage.
template <typename BT>
__global__ __launch_bounds__(512, 4) void k_gemm(
    const BT* __restrict__ Bsrc, const u16* __restrict__ Ah,
    u16* __restrict__ Dout) {
  constexpr bool BF32 = std::is_same_v<BT, float>;
  __shared__ __align__(16) u16 As[2][APAD * 32];   // 2 x 13,312 B
  __shared__ __align__(16) u16 Bl[2][32 * BROW];   // 2 x 8,704 B
  const int tid  = threadIdx.x;
  const int lane = tid & 63;
  const int wave = tid >> 6;
  const int l15  = lane & 15;
  const int kg   = lane >> 4;
  // bijective XCD swizzle (m204): nwg=2500 = 8*312 + 4
  const int orig = blockIdx.x;
  const int xcd = orig & 7, pos = orig >> 3;
  const int blk = (xcd < 4 ? xcd * 313 : 4 * 313 + (xcd - 4) * 312) + pos;
  const int nblk = blk * 128;
  const int n0   = nblk + wave * 16 + l15;

  const int arow0 = tid >> 2,  ac4 = tid & 3;            // u = tid      (<832)
  const int arow1 = (tid + 512) >> 2, ac4b = tid & 3;    // u = tid+512  (<832)
  const bool a1v  = tid < 320;
  const int brow  = tid >> 4,  bc8 = tid & 15;           // 32 rows x 16 chunks

  int4 ra0, ra1;
  f32x4 rb0, rb1;            // ci raw B (8 floats)
  ushort8 rbh;               // cj raw B halves

#define GLOAD(S)                                                              \
  { ra0 = *(const int4*)(Ah + arow0 * KPAD + (S) * 32 + ac4 * 8);             \
    if (a1v) ra1 = *(const int4*)(Ah + arow1 * KPAD + (S) * 32 + ac4b * 8);   \
    int r = (S) * 32 + brow; if (r > 199) r = 199;                            \
    if constexpr (BF32) {                                                     \
      const float* bp = (const float*)Bsrc + (long)r * SJK + nblk + bc8 * 8;  \
      rb0 = *(const f32x4*)bp; rb1 = *(const f32x4*)(bp + 4);                 \
    } else {                                                                  \
      rbh = *(const ushort8*)((const u16*)Bsrc + (long)r * SJK + nblk + bc8 * 8); \
    } }

#define DSWRITE(BUF)                                                          \
  { *(int4*)(&As[BUF][arow0 * 32 + ac4 * 8]) = ra0;                           \
    if (a1v) *(int4*)(&As[BUF][arow1 * 32 + ac4b * 8]) = ra1;                 \
    if constexpr (BF32) {                                                     \
      ushort8 h;                                                              \
      _Pragma("unroll")                                                       \
      for (int e = 0; e < 4; ++e) {                                           \
        h[e]     = __builtin_bit_cast(u16, (_Float16)rb0[e]);                 \
        h[e + 4] = __builtin_bit_cast(u16, (_Float16)rb1[e]);                 \
      }                                                                       \
      *(ushort8*)(&Bl[BUF][brow * BROW + bc8 * 8]) = h;                       \
    } else {                                                                  \
      *(ushort8*)(&Bl[BUF][brow * BROW + bc8 * 8]) = rbh;                     \
    } }

#define COMPUTE(BUF)                                                          \
  { half8 bh;                                                                 \
    _Pragma("unroll")                                                         \
    for (int e = 0; e < 8; ++e)                                               \
      bh[e] = __builtin_bit_cast(_Float16,                                    \
                  Bl[BUF][(kg * 8 + e) * BROW + wave * 16 + l15]);            \
    _Pragma("unroll")                                                         \
    for (int t = 0; t < 13; ++t) {                                            \
      half8 ah = *(const half8*)(&As[BUF][(t * 16 + l15) * 32 + kg * 8]);     \
      acc[t] = __builtin_amdgcn_mfma_f32_16x16x32_f16(ah, bh, acc[t], 0,0,0); \
    } }

  f32x4 acc[13];
#pragma unroll
  for (int t = 0; t < 13; ++t)
#pragma unroll
    for (int q = 0; q < 4; ++q) acc[t][q] = 0.f;

  GLOAD(0)
  DSWRITE(0)
  __syncthreads();
  // single barrier per stage (T3 2-phase): DSWRITE targets the opposite
  // buffer from COMPUTE; readers of that buffer finished before the
  // previous barrier -> no mid-stage barrier needed.
#pragma unroll
  for (int s = 0; s < 7; ++s) {
    if (s < 6) GLOAD(s + 1)
    COMPUTE(s & 1)
    if (s < 6) {
      DSWRITE((s + 1) & 1)
      __syncthreads();
    }
  }

  // permuted store: n0 = (j, m2); D[j*320000 + row*1600 + m2]
  const int j  = (u32)n0 / 1600u;
  const int m2 = n0 - j * 1600;
  u16* dbase = Dout + (long)j * SJK + m2;
#pragma unroll
  for (int t = 0; t < 13; ++t) {
    const int rb = t * 16 + kg * 4;
#pragma unroll
    for (int r = 0; r < 4; ++r) {
      const int row = rb + r;
      if (row < N12)
        dbase[(long)row * SKS] = __builtin_bit_cast(u16, (_Float16)acc[t][r]);
    }
  }
#undef GLOAD
#undef DSWRITE
#undef COMPUTE
}

// ------- contract k + elementwise, MFMA form (fp16 T2 input) --------------
// Per wave: one ab. A slab loaded as 4 contiguous ushort8/lane, scattered to
// a wave-private transposed LDS slab [s][64] (phys_k = k ^ ((s&7)<<3));
// fragments = aligned ds_read_b128. Pad rows zeroed. (R17 structure.)
__global__ __launch_bounds__(256, 6) void k_contract_k_mfma(
    const u16* __restrict__ T2h, const float* __restrict__ TT,
    const u16* __restrict__ K3B, float* __restrict__ reg) {
  __shared__ __align__(16) u16 bs[K3B_HALVES];   // 8 KB
  __shared__ __align__(16) u16 sl[4][32 * 64];   // 4 x 4 KB per-wave slabs
  const int tid  = threadIdx.x;
  {
    const int4* src = (const int4*)K3B;
    int4* dst = (int4*)bs;
    dst[tid] = src[tid];
    dst[tid + 256] = src[tid + 256];
  }
  const int lane = tid & 63;
  const int wave = tid >> 6;
  const int l15  = lane & 15;
  const int kg   = lane >> 4;
  const int ab   = blockIdx.x * 4 + wave;         // 0..39999
  const int base = ab * SKS;
  u16* s_ = &sl[wave][0];

  // zero the slab (pad k=50..63 must be 0.0, not garbage-NaN)
  {
    ushort8 z;
#pragma unroll
    for (int e = 0; e < 8; ++e) z[e] = 0;
#pragma unroll
    for (int c = 0; c < 4; ++c)
      *(ushort8*)(&s_[(c * 64 + lane) * 8]) = z;
  }
  // contiguous slab load + transposed swizzled scatter (wave-private; DS ops
  // from one wave execute in order -> no barrier needed)
#pragma unroll
  for (int c = 0; c < 4; ++c) {
    const int ch = c * 64 + lane;                 // 16B chunk id, 200 valid
    if (ch < 200) {
      ushort8 v = *(const ushort8*)(T2h + base + ch * 8);
      const int k  = ch >> 2;                     // 0..49
      const int s0 = (ch & 3) * 8;                // 0,8,16,24
#pragma unroll
      for (int j = 0; j < 8; ++j)
        s_[(s0 + j) * 64 + (k ^ (j << 3))] = v[j];   // (s0+j)&7 == j
    }
  }
  __syncthreads();                                // bs ready

  half8 bf[2][4];
#pragma unroll
  for (int ks = 0; ks < 2; ++ks)
#pragma unroll
    for (int cs = 0; cs < 4; ++cs)
      bf[ks][cs] = *(const half8*)(bs + ((ks * 4 + cs) * 64 + lane) * 8);

  // A fragments from the transposed slab: s = rt*16+l15, k-run = ks*32+kg*8+e
  half8 af[2][2];
#pragma unroll
  for (int rt = 0; rt < 2; ++rt)
#pragma unroll
    for (int ks = 0; ks < 2; ++ks) {
      const int s = rt * 16 + l15;
      af[rt][ks] = *(const half8*)(
          &s_[s * 64 + ((ks * 32 + kg * 8) ^ ((s & 7) << 3))]);
    }

  f32x4 acc[2][4];
#pragma unroll
  for (int rt = 0; rt < 2; ++rt)
#pragma unroll
    for (int cs = 0; cs < 4; ++cs)
#pragma unroll
      for (int q = 0; q < 4; ++q) acc[rt][cs][q] = 0.f;

#pragma unroll
  for (int rt = 0; rt < 2; ++rt)
#pragma unroll
    for (int ks = 0; ks < 2; ++ks)
#pragma unroll
      for (int cs = 0; cs < 4; ++cs)
        acc[rt][cs] = __builtin_amdgcn_mfma_f32_16x16x32_f16(
            af[rt][ks], bf[ks][cs], acc[rt][cs], 0, 0, 0);

  // epilogue: both rt halves of each 128B line stored back-to-back (R10 fix)
#pragma unroll
  for (int cs = 0; cs < 4; ++cs) {
    const int c = cs * 16 + l15;
    if (c < N3) {
      const int o0 = base + c * R2 + kg * 4;
      f32x4 tv0 = *(const f32x4*)(TT + o0);
      f32x4 tv1 = *(const f32x4*)(TT + o0 + 16);
      f32x4 r0, r1;
#pragma unroll
      for (int q = 0; q < 4; ++q) {
        r0[q] = acc[0][cs][q] * tv0[q];
        r1[q] = acc[1][cs][q] * tv1[q];
      }
      *(f32x4*)(reg + o0) = r0;
      *(f32x4*)(reg + o0 + 16) = r1;
    }
  }
}

// ------------- gather (2-wide): out[n,s..s+1] = sum_k K3[c,k]*T2[a,b,k,s..s+1]
__global__ __launch_bounds__(256) void k_gather2(
    const u16* __restrict__ T2h, const float* __restrict__ K3,
    const int* __restrict__ idx, float* __restrict__ out) {
  int g = blockIdx.x * 256 + threadIdx.x;   // 1.6M threads exactly
  int n = g >> 4, sp = (g & 15) * 2;
  int a = idx[n * 3 + 0], b = idx[n * 3 + 1], c = idx[n * 3 + 2];
  const u16* t2 = T2h + a * SJK + b * SKS + sp;
  const float* k3r = K3 + c * N3;
  float acc0 = 0.f, acc1 = 0.f;
#pragma unroll
  for (int k = 0; k < N3; ++k) {
    ushort2 v = *(const ushort2*)(t2 + k * R2);
    acc0 = fmaf(k3r[k], (float)__builtin_bit_cast(_Float16, v.x), acc0);
    acc1 = fmaf(k3r[k], (float)__builtin_bit_cast(_Float16, v.y), acc1);
  }
  *(float2*)(out + n * R2 + sp) = make_float2(acc0, acc1);
}

// ---------------- fallback path helpers (unused when ws >= 128 MB) ---------
__global__ __launch_bounds__(256) void k_transpose(
    const float* __restrict__ K2, float* __restrict__ K2T) {
  int t = blockIdx.x * 256 + threadIdx.x;
  if (t < N12 * N12) {
    int i = t / N12, a = t % N12;
    K2T[t] = K2[a * N12 + i];
  }
}

__global__ __launch_bounds__(256) void k_fallback_ci(
    const float* __restrict__ TT, const float* __restrict__ K1T,
    float* __restrict__ T1) {
  const int m  = blockIdx.x * 256 + threadIdx.x;
  const int a0 = blockIdx.y * 50;
  float acc[50];
#pragma unroll
  for (int aa = 0; aa < 50; ++aa) acc[aa] = 0.f;
#pragma unroll 2
  for (int i = 0; i < N12; ++i) {
    float v = TT[i * SJK + m];
    const float* kr = K1T + i * N12 + a0;
#pragma unroll
    for (int aa = 0; aa < 50; ++aa) acc[aa] = fmaf(kr[aa], v, acc[aa]);
  }
#pragma unroll
  for (int aa = 0; aa < 50; ++aa) T1[(a0 + aa) * SJK + m] = acc[aa];
}

__global__ __launch_bounds__(256) void k_contract_j_inplace(
    float* T12, const float* __restrict__ K2T) {
  __shared__ float lds[N12 * 80];   // 64000 B
  const int a    = blockIdx.y;
  const int m0   = blockIdx.x * 80;
  const int base = a * SJK + m0;
  for (int t = threadIdx.x; t < N12 * 80; t += 256) {
    int j = t / 80, ml = t % 80;
    lds[t] = T12[base + j * SKS + ml];
  }
  __syncthreads();
  for (int o = threadIdx.x; o < N12 * 80; o += 256) {
    int b = o / 80, ml = o % 80;
    float acc = 0.f;
#pragma unroll 4
    for (int j = 0; j < N12; ++j)
      acc = fmaf(K2T[j * N12 + b], lds[j * 80 + ml], acc);
    T12[base + b * SKS + ml] = acc;
  }
}

__global__ __launch_bounds__(256) void k_gather_f32(
    const float* T2, const float* __restrict__ K3,
    const int* __restrict__ idx, float* __restrict__ out) {
  int g = blockIdx.x * 256 + threadIdx.x;
  int n = g >> 5, s = g & 31;
  int a = idx[n * 3 + 0], b = idx[n * 3 + 1], c = idx[n * 3 + 2];
  const float* t2 = T2 + a * SJK + b * SKS + s;
  const float* k3r = K3 + c * N3;
  float acc = 0.f;
#pragma unroll
  for (int k = 0; k < N3; ++k) acc = fmaf(k3r[k], t2[k * R2], acc);
  out[g] = acc;
}

__global__ __launch_bounds__(256) void k_contract_k_reg(
    const float* T2, const float* __restrict__ TT,
    const float* __restrict__ K3, float* reg) {
  const int t  = blockIdx.x * 256 + threadIdx.x;
  const int s  = t & 31;
  const int ab = t >> 5;
  const int base = ab * SKS + s;
  float v[N3];
#pragma unroll
  for (int k = 0; k < N3; ++k) v[k] = T2[base + k * R2];
  for (int c = 0; c < N3; ++c) {
    const float* k3r = K3 + c * N3;
    float a0 = 0.f, a1 = 0.f, a2 = 0.f, a3 = 0.f;
#pragma unroll
    for (int k = 0; k < 48; k += 4) {
      a0 = fmaf(k3r[k],     v[k],     a0);
      a1 = fmaf(k3r[k + 1], v[k + 1], a1);
      a2 = fmaf(k3r[k + 2], v[k + 2], a2);
      a3 = fmaf(k3r[k + 3], v[k + 3], a3);
    }
    a0 = fmaf(k3r[48], v[48], a0);
    a1 = fmaf(k3r[49], v[49], a1);
    const int o = base + c * R2;
    reg[o] = ((a0 + a1) + (a2 + a3)) * TT[o];
  }
}

extern "C" void kernel_launch(void* const* d_in, const int* in_sizes, int n_in,
                              void* d_out, int out_size, void* d_ws, size_t ws_size,
                              hipStream_t stream) {
  const float* TT  = (const float*)d_in[0];
  const float* K1  = (const float*)d_in[1];
  const float* K2  = (const float*)d_in[2];
  const float* K3  = (const float*)d_in[3];
  const int*   idx = (const int*)d_in[4];

  float* out = (float*)d_out;          // [0, 3.2M)
  float* reg = out + OUT_ELEMS;        // [3.2M, 67.2M) -- also T1h scratch
  // Prepped fp16 K matrices + K3B fragment pack live at the start of the out
  // region (dead before k_gather2 overwrites out).
  u16* kh = (u16*)d_out;
  const int matoff = APAD * KPAD;               // K2 offset within kh
  const u16* k3b = kh + 2 * matoff;             // K3B offset

  k_prep<<<dim3((2 * matoff + K3B_HALVES + 255) / 256), 256, 0, stream>>>(
      K1, K2, K3, kh);

  const size_t need = (size_t)NTOT * sizeof(u16);   // 128,000,000 B
  if (ws_size >= need) {
    u16* T1h = (u16*)reg;          // 128 MB in reg region (dead before ck)
    u16* T2h = (u16*)d_ws;         // 128 MB
    // contract i: T1h stored PERMUTED as [j][a*1600+m2]
    k_gemm<float><<<dim3(2500), 512, 0, stream>>>(TT, kh, T1h);
    // contract j: reads T1h rows contiguously; T2h stored as [a][b*1600+m2]
    k_gemm<u16><<<dim3(2500), 512, 0, stream>>>(T1h, kh + matoff, T2h);
    // contract k (writes reg fp32 over T1h region -- T1 dead; K3B still live)
    k_contract_k_mfma<<<dim3(40000 / 4), 256, 0, stream>>>(T2h, TT, k3b, reg);
    // gather last (clobbers kh/k3b region)
    k_gather2<<<dim3(OUT_ELEMS / 512), 256, 0, stream>>>(T2h, K3, idx, out);
  } else {
    // fp32 fallback (never taken on this harness: rounds 1-17 ran ws path)
    float* k1t = out;                       // scratch inside out region
    float* k2t = out + N12 * N12;
    k_transpose<<<dim3((N12 * N12 + 255) / 256), 256, 0, stream>>>(K1, k1t);
    k_transpose<<<dim3((N12 * N12 + 255) / 256), 256, 0, stream>>>(K2, k2t);
    k_fallback_ci<<<dim3(SJK / 256, 4), 256, 0, stream>>>(TT, k1t, reg);
    k_contract_j_inplace<<<dim3(20, N12), 256, 0, stream>>>(reg, k2t);
    k_gather_f32<<<dim3(OUT_ELEMS / 256), 256, 0, stream>>>(reg, K3, idx, out);
    k_contract_k_reg<<<dim3(40000 * 32 / 256), 256, 0, stream>>>(reg, TT, K3, reg);
  }
}